// Round 2
// baseline (1894.446 us; speedup 1.0000x reference)
//
#include <hip/hip_runtime.h>

// ---------------------------------------------------------------------------
// uOT loss (unbalanced Sinkhorn, eps=0.1, rho=1, 50 iters + extrapolation x2)
// One workgroup (512 threads = 8 waves) per sample; 4 samples.
//
// Math: track phi = e^{f/eps} = s^{-tau}, psi' = b * e^{g/eps} = b * t^{-tau}.
//   f-update: S[i][j] = sum_m (psi'_m * A[i][m]) * B[j][m]        (MFMA GEMM)
//   g-update: P[i][m] = sum_j (a*phi)[i][j] * B[j][m]             (MFMA GEMM)
//             t_m = sum_i A[i][m] * P[i][m]
// where A[i][m] = exp(-5(gx_i - ymx_m)^2), B[j][m] = exp(-5(gy_j - ymy_m)^2).
// ---------------------------------------------------------------------------

typedef __attribute__((ext_vector_type(4))) float f32x4;
typedef __attribute__((ext_vector_type(8))) short short8;

// LDS layout (byte offsets)
#define OFF_BMJ   0         // bf16 [256 m][128 j], swz ^((m&15)<<4)   (g-GEMM B-op)
#define OFF_WQ    65536     // bf16 [128 i][64 mm], swz ^((i&7)<<4)    (f-GEMM A-op chunk)
#define OFF_V     81920     // bf16 [128 i][128 j], swz ^((i&15)<<4)   (g-GEMM A-op)
#define OFF_A     114688    // bf16 [128 i][128 j]  (clipped density)
#define OFF_YMX   147456    // f32[256]
#define OFF_YMY   148480    // f32[256]
#define OFF_PSI   149504    // f32[256]  psi' (includes b factor)
#define OFF_NB    150528    // f32[256]  new_b
#define OFF_TB    151552    // f32[256]  last t
#define OFF_TP    152576    // f32[2][256] cross-wave t partials
#define OFF_RED   154624    // f32[8]
#define LDS_SIZE  154688

#define TAU_F     0.9090909090909091f     // rho/(rho+eps)
#define TEPS_F    0.09090909090909091f    // tau*eps
#define LAMB_F    0.005354280739427885f   // 0.8*sigmoid(-5)
#define NEG5L2E  -7.213475204444817f      // -(1/(2*eps)) * log2(e)

static __device__ __forceinline__ float fexp2(float x) { return exp2f(x); }   // v_exp_f32
static __device__ __forceinline__ float flog2(float x) { return log2f(x); }   // v_log_f32

static __device__ __forceinline__ float b2f(unsigned short u) {
  union { unsigned int i; float f; } v; v.i = ((unsigned int)u) << 16; return v.f;
}
static __device__ __forceinline__ unsigned short f2b(float f) {
  union { float f; unsigned int i; } v; v.f = f;
  unsigned int b = v.i + 0x7fffu + ((v.i >> 16) & 1u);   // RNE
  return (unsigned short)(b >> 16);
}
static __device__ __forceinline__ f32x4 mfma16(uint4 a, uint4 b, f32x4 c) {
  return __builtin_amdgcn_mfma_f32_16x16x32_bf16(
      __builtin_bit_cast(short8, a), __builtin_bit_cast(short8, b), c, 0, 0, 0);
}

// ---- f-update: S = (psi'.A) . B^T, accumulated in fA (wave tile 32i x 64j) ----
static __device__ __forceinline__ void f_update(f32x4 fA[2][4],
    const unsigned short* __restrict__ Ag, const unsigned short* __restrict__ Bf,
    char* smem, int t, int l, int fi, int fj) {
  const float* psi = (const float*)(smem + OFF_PSI);
  #pragma unroll
  for (int it = 0; it < 2; ++it)
    #pragma unroll
    for (int jt = 0; jt < 4; ++jt) { f32x4 z = {0.f, 0.f, 0.f, 0.f}; fA[it][jt] = z; }

  #pragma unroll 1
  for (int c = 0; c < 4; ++c) {            // m-chunks of 64
    __syncthreads();                        // Wq free (prev readers done)
    // build Wq[i][mm] = psi[c*64+mm] * A[i][c*64+mm]
    #pragma unroll
    for (int p = 0; p < 2; ++p) {
      int i  = p * 64 + (t >> 3);
      int m8 = (t & 7) * 8;
      int mg = c * 64 + m8;
      uint4 araw = *(const uint4*)(Ag + i * 256 + mg);
      float4 p0 = *(const float4*)(psi + mg);
      float4 p1 = *(const float4*)(psi + mg + 4);
      float pv0 = p0.x, pv1 = p0.y, pv2 = p0.z, pv3 = p0.w;
      float pv4 = p1.x, pv5 = p1.y, pv6 = p1.z, pv7 = p1.w;
      const unsigned int* ar = (const unsigned int*)&araw;
      uint4 o;
      o.x = (unsigned int)f2b(b2f((unsigned short)(ar[0] & 0xffffu)) * pv0)
          | ((unsigned int)f2b(b2f((unsigned short)(ar[0] >> 16)) * pv1) << 16);
      o.y = (unsigned int)f2b(b2f((unsigned short)(ar[1] & 0xffffu)) * pv2)
          | ((unsigned int)f2b(b2f((unsigned short)(ar[1] >> 16)) * pv3) << 16);
      o.z = (unsigned int)f2b(b2f((unsigned short)(ar[2] & 0xffffu)) * pv4)
          | ((unsigned int)f2b(b2f((unsigned short)(ar[2] >> 16)) * pv5) << 16);
      o.w = (unsigned int)f2b(b2f((unsigned short)(ar[3] & 0xffffu)) * pv6)
          | ((unsigned int)f2b(b2f((unsigned short)(ar[3] >> 16)) * pv7) << 16);
      *(uint4*)(smem + OFF_WQ + ((i * 128 + m8 * 2) ^ ((i & 7) << 4))) = o;
    }
    __syncthreads();
    // B fragments for this chunk from global (m-blocked layout, coalesced)
    uint4 bfr[2][4];
    #pragma unroll
    for (int ks = 0; ks < 2; ++ks)
      #pragma unroll
      for (int jt = 0; jt < 4; ++jt) {
        int j = fj * 64 + jt * 16 + (l & 15);
        int mblk = c * 8 + ks * 4 + (l >> 4);
        bfr[ks][jt] = *(const uint4*)(Bf + ((mblk * 128 + j) << 3));
      }
    #pragma unroll
    for (int ks = 0; ks < 2; ++ks) {
      uint4 wfr[2];
      #pragma unroll
      for (int it = 0; it < 2; ++it) {
        int i  = fi * 32 + it * 16 + (l & 15);
        int mm = ks * 32 + 8 * (l >> 4);
        wfr[it] = *(const uint4*)(smem + OFF_WQ + ((i * 128 + mm * 2) ^ ((i & 7) << 4)));
      }
      #pragma unroll
      for (int it = 0; it < 2; ++it)
        #pragma unroll
        for (int jt = 0; jt < 4; ++jt)
          fA[it][jt] = mfma16(wfr[it], bfr[ks][jt], fA[it][jt]);
    }
  }
}

// ---- g-update: V = a*phi from fA; P = V.B; t = col-reduce(A.P); psi update ----
// mode 0: phase-A normal (b=1); mode 1: phase-C normal (b=new_b); mode 2: residual
static __device__ __forceinline__ void g_update(const f32x4 fA[2][4],
    const unsigned short* __restrict__ Ag, char* smem, int t, int l,
    int fi, int fj, int gi, int gm, int mode) {
  unsigned short* a_l = (unsigned short*)(smem + OFF_A);
  // V build: phi = s^{-tau}; V[i][j] = a*phi (bf16, swizzled)
  #pragma unroll
  for (int it = 0; it < 2; ++it)
    #pragma unroll
    for (int jt = 0; jt < 4; ++jt)
      #pragma unroll
      for (int e = 0; e < 4; ++e) {
        float s = fA[it][jt][e];
        float phi = fexp2(-TAU_F * flog2(s));
        int i = fi * 32 + it * 16 + 4 * (l >> 4) + e;   // C/D: row=4*(l>>4)+reg
        int j = fj * 64 + jt * 16 + (l & 15);           //      col=l&15
        float av = b2f(a_l[i * 128 + j]);
        *(unsigned short*)(smem + OFF_V + ((i * 256 + j * 2) ^ ((i & 15) << 4))) =
            f2b(av * phi);
      }
  __syncthreads();

  f32x4 gA[4][4];
  #pragma unroll
  for (int it = 0; it < 4; ++it)
    #pragma unroll
    for (int mt = 0; mt < 4; ++mt) { f32x4 z = {0.f, 0.f, 0.f, 0.f}; gA[it][mt] = z; }
  #pragma unroll
  for (int ks = 0; ks < 4; ++ks) {          // K = j, 32 per step
    int j0 = ks * 32 + 8 * (l >> 4);
    uint4 vfr[4], bfr[4];
    #pragma unroll
    for (int it = 0; it < 4; ++it) {
      int i = gi * 64 + it * 16 + (l & 15);
      vfr[it] = *(const uint4*)(smem + OFF_V + ((i * 256 + j0 * 2) ^ ((i & 15) << 4)));
    }
    #pragma unroll
    for (int mt = 0; mt < 4; ++mt) {
      int m = gm * 64 + mt * 16 + (l & 15);
      bfr[mt] = *(const uint4*)(smem + OFF_BMJ + ((m * 256 + j0 * 2) ^ ((m & 15) << 4)));
    }
    #pragma unroll
    for (int it = 0; it < 4; ++it)
      #pragma unroll
      for (int mt = 0; mt < 4; ++mt)
        gA[it][mt] = mfma16(vfr[it], bfr[mt], gA[it][mt]);
  }
  // t-reduce: t_m = sum_i A[i][m] * P[i][m]
  float* tp = (float*)(smem + OFF_TP);
  #pragma unroll
  for (int mt = 0; mt < 4; ++mt) {
    int m = gm * 64 + mt * 16 + (l & 15);
    float acc = 0.f;
    #pragma unroll
    for (int it = 0; it < 4; ++it)
      #pragma unroll
      for (int e = 0; e < 4; ++e) {
        int i = gi * 64 + it * 16 + 4 * (l >> 4) + e;
        acc += b2f(Ag[i * 256 + m]) * gA[it][mt][e];
      }
    acc += __shfl_xor(acc, 16);
    acc += __shfl_xor(acc, 32);
    if ((l & 48) == 0) tp[gi * 256 + m] = acc;
  }
  __syncthreads();
  if (t < 256) {
    int m = t;
    float tm = tp[m] + tp[256 + m];
    float* psi = (float*)(smem + OFF_PSI);
    float* nb  = (float*)(smem + OFF_NB);
    float* tb  = (float*)(smem + OFF_TB);
    if (mode == 2) {
      float r   = psi[m] * tm - 1.f;               // residual (b=1 in phase A)
      float nbv = fmaxf(1.f + LAMB_F * r, 1e-8f);  // new_b
      nb[m] = nbv;
      psi[m] = nbv;                                // reset psi' = new_b * 1 for phase C
    } else {
      float ps = fexp2(-TAU_F * flog2(tm));        // t^{-tau}
      psi[m] = (mode == 1 ? nb[m] : 1.f) * ps;
      tb[m] = tm;
    }
  }
  __syncthreads();
}

__global__ void __launch_bounds__(512, 2)
uot_kernel(const float* __restrict__ dens, const float* __restrict__ pts,
           float* __restrict__ out, unsigned short* __restrict__ ws) {
  extern __shared__ char smem[];
  const int s = blockIdx.x;
  const int t = threadIdx.x;
  const int l = t & 63;
  const int w = t >> 6;
  const int fi = w >> 1, fj = w & 1;   // f-GEMM wave tile: rows 32*fi, cols 64*fj
  const int gi = w >> 2, gm = w & 3;   // g-GEMM wave tile: rows 64*gi, cols 64*gm
  unsigned short* Ag = ws + (size_t)s * 32768;         // A [128 i][256 m] bf16
  unsigned short* Bf = ws + (size_t)(4 + s) * 32768;   // B blocked [32 mblk][128 j][8 me]
  const float* dp = dens + s * 16384;
  const float* pp = pts + s * 512;
  float* ymx = (float*)(smem + OFF_YMX);
  float* ymy = (float*)(smem + OFF_YMY);
  float* psi = (float*)(smem + OFF_PSI);
  float* nb  = (float*)(smem + OFF_NB);
  unsigned short* a_l = (unsigned short*)(smem + OFF_A);

  // ---- init ----
  if (t < 256) {
    ymx[t] = pp[2 * t] * (1.f / 256.f);
    ymy[t] = pp[2 * t + 1] * (1.f / 256.f);
    psi[t] = 1.f;
    nb[t]  = 1.f;
  }
  __syncthreads();
  #pragma unroll 1
  for (int r = 0; r < 64; ++r) {
    int flat = r * 512 + t;
    { int i = flat >> 8, m = flat & 255;
      float dx = (i + 0.5f) * (1.f / 128.f) - ymx[m];
      Ag[flat] = f2b(fexp2(dx * dx * NEG5L2E)); }
    { int me = flat & 7, j = (flat >> 3) & 127, mblk = flat >> 10;
      float dy = (j + 0.5f) * (1.f / 128.f) - ymy[mblk * 8 + me];
      Bf[flat] = f2b(fexp2(dy * dy * NEG5L2E)); }
    { int m = flat >> 7, j = flat & 127;
      float dy = (j + 0.5f) * (1.f / 128.f) - ymy[m];
      *(unsigned short*)(smem + OFF_BMJ + ((m * 256 + j * 2) ^ ((m & 15) << 4))) =
          f2b(fexp2(dy * dy * NEG5L2E)); }
  }
  #pragma unroll 1
  for (int r = 0; r < 32; ++r) {
    int flat = r * 512 + t;
    a_l[flat] = f2b(fmaxf(dp[flat], 1e-8f));
  }
  __threadfence();
  __syncthreads();

  // ---- two Sinkhorn runs ----
  f32x4 fA[2][4];
  #pragma unroll 1
  for (int phase = 0; phase < 2; ++phase) {
    #pragma unroll 1
    for (int iter = 0; iter < 51; ++iter) {
      f_update(fA, Ag, Bf, smem, t, l, fi, fj);
      if (iter < 50) g_update(fA, Ag, smem, t, l, fi, fj, gi, gm, phase);
    }
    if (phase == 0) g_update(fA, Ag, smem, t, l, fi, fj, gi, gm, 2);  // residual
  }

  // ---- loss: 1.05 * ( sum_n a*(1 - s^{tau*eps}) + sum_m nb*(1 - t^{tau*eps}) ) ----
  float ls = 0.f;
  #pragma unroll
  for (int it = 0; it < 2; ++it)
    #pragma unroll
    for (int jt = 0; jt < 4; ++jt)
      #pragma unroll
      for (int e = 0; e < 4; ++e) {
        float sv = fA[it][jt][e];
        int i = fi * 32 + it * 16 + 4 * (l >> 4) + e;
        int j = fj * 64 + jt * 16 + (l & 15);
        float av = b2f(a_l[i * 128 + j]);
        ls += av * (1.f - fexp2(TEPS_F * flog2(sv)));
      }
  #pragma unroll
  for (int off = 32; off >= 1; off >>= 1) ls += __shfl_xor(ls, off);
  float* red = (float*)(smem + OFF_RED);
  if (l == 0) red[w] = ls;
  __syncthreads();
  if (t == 0) {
    float* tb = (float*)(smem + OFF_TB);
    float la = 0.f;
    #pragma unroll 1
    for (int i = 0; i < 8; ++i) la += red[i];
    float lb = 0.f;
    #pragma unroll 1
    for (int m = 0; m < 256; ++m)
      lb += nb[m] * (1.f - fexp2(TEPS_F * flog2(tb[m])));
    atomicAdd(out, 1.05f * (la + lb));
  }
}

extern "C" void kernel_launch(void* const* d_in, const int* in_sizes, int n_in,
                              void* d_out, int out_size, void* d_ws, size_t ws_size,
                              hipStream_t stream) {
  const float* dens = (const float*)d_in[0];
  const float* pts  = (const float*)d_in[1];
  float* out = (float*)d_out;
  (void)hipMemsetAsync(d_out, 0, sizeof(float), stream);
  if (ws_size < 524288) return;  // need 4 * (64KB A + 64KB B) tables
  (void)hipFuncSetAttribute(reinterpret_cast<const void*>(uot_kernel),
                            hipFuncAttributeMaxDynamicSharedMemorySize, LDS_SIZE);
  hipLaunchKernelGGL(uot_kernel, dim3(4), dim3(512), LDS_SIZE, stream,
                     dens, pts, out, (unsigned short*)d_ws);
}